// Round 5
// baseline (199.368 us; speedup 1.0000x reference)
//
#include <hip/hip_runtime.h>

// PositionNet, two-kernel MFMA bf16x3 edition.
//   K0: weight pre-split fp32 -> bf16 hi/lo, fragment-major layout (688,128 B ws)
//   K1: per-sample GEMM [64px x 768] x [768 x 200], logits (+bias) -> d_out hm
//       region (layout [b][o][px] == [b][j][d][h,w]); A hi/lo double-buffered
//       in 32 KB LDS (fragment-major, conflict-free); B direct global->VGPR.
//   K2: in-place softmax(512) + soft-argmax per (b,joint), one wave each.
//
// Numerics: bf16 hi/lo split, hh+hl+lh MFMA terms (~2^-16 rel logit error).
// Fragment k-addressing identical for A and B (k = kc*32 + (lane>>4)*8 + e),
// so any HW k-slot permutation cancels; relies on lane&15 = free-dim and the
// m89-verified C/D layout (col=lane&15, row=(lane>>4)*4+reg) — both already
// validated by round-3's passing run.

typedef __attribute__((ext_vector_type(4))) float f32x4;
typedef __attribute__((ext_vector_type(8))) short bf16x8;
typedef __attribute__((ext_vector_type(4))) unsigned short us4;
typedef __attribute__((ext_vector_type(4))) unsigned int u32x4;

namespace {
constexpr int kB = 512, kC = 768, kP = 64, kO = 200, kJ = 25;
constexpr int kKT = 64, kSteps = 12;   // K = 12 steps x 64 channels
constexpr int kNT = 13, kNTP = 14;     // 13 live 16-wide N tiles, padded to 14
// ws (weights): [half][t=12][kc=2][nt=14][g=4][ml=16][e=8] bf16
constexpr int kWsHalf = 12 * 2 * 14 * 512;  // 172,032 shorts per half
constexpr size_t kHmOut = (size_t)kB * kJ * 512;
}  // namespace

__device__ inline unsigned short f2bf(float x) {  // RNE fp32 -> bf16 bits
  union { float f; unsigned u; } c; c.f = x;
  unsigned r = c.u + 0x7FFFu + ((c.u >> 16) & 1u);
  return (unsigned short)(r >> 16);
}
__device__ inline float bf2f(unsigned short h) {
  union { unsigned u; float f; } c; c.u = ((unsigned)h) << 16;
  return c.f;
}

// ---- K0: w[200][768] fp32 -> ws fragment-major bf16 hi/lo ----
__global__ __launch_bounds__(256) void weight_split_kernel(
    const float* __restrict__ w, unsigned short* __restrict__ ws) {
  const int id = blockIdx.x * 256 + threadIdx.x;  // 43,008 frag-tasks
  if (id >= 43008) return;
  const int ml = id & 15, g = (id >> 4) & 3;
  const int id2 = id >> 6;
  const int nt = id2 % 14;
  const int q = id2 / 14;
  const int kc = q & 1;
  const int q2 = q >> 1;
  const int t = q2 % 12;
  const int half = q2 / 12;
  const int n = nt * 16 + ml;
  const int kb = t * 64 + kc * 32 + g * 8;
  float v[8];
#pragma unroll
  for (int i = 0; i < 8; ++i)
    v[i] = (n < kO) ? w[(size_t)n * kC + kb + i] : 0.f;
  unsigned short o8[8];
#pragma unroll
  for (int i = 0; i < 8; ++i) {
    const unsigned short hi = f2bf(v[i]);
    o8[i] = half ? f2bf(v[i] - bf2f(hi)) : hi;
  }
  unsigned short* dst =
      ws + (size_t)half * kWsHalf +
      ((((size_t)(t * 2 + kc) * 14 + nt) * 4 + g) * 16 + ml) * 8;
  *(us4*)dst = us4{o8[0], o8[1], o8[2], o8[3]};
  *(us4*)(dst + 4) = us4{o8[4], o8[5], o8[6], o8[7]};
}

// A LDS: fragment-major [buf][half][kc][g][px] x 16B -> 32,768 B total.
__device__ inline int afrag(int buf, int half, int kc, int g, int px) {
  return ((((buf * 2 + half) * 2 + kc) * 4 + g) * 64 + px) * 16;  // bytes
}

__global__ __launch_bounds__(256, 3) void gemm_kernel(
    const float* __restrict__ img, const unsigned short* __restrict__ wsb,
    const float* __restrict__ bias, float* __restrict__ out) {
  __shared__ __align__(16) char smem[32768];

  const int b = blockIdx.x;
  const int tid = threadIdx.x;
  const int lane = tid & 63;
  const int wid = tid >> 6;
  const int m_l = lane & 15;  // free-dim index
  const int g = lane >> 4;    // k-slot group
  const float* __restrict__ imgb = img + (size_t)b * kC * kP;

  // staging coords: px = lane, c0 = wave-uniform 16-channel slice
  const int px = lane;
  const int c0 = wid * 16;
  const int skc = c0 >> 5;          // 0 or 1
  const int sg0 = (c0 & 31) >> 3;   // 0 or 2

  f32x4 acc[4][4];  // [ni][mt]
#pragma unroll
  for (int i = 0; i < 4; ++i)
#pragma unroll
    for (int j = 0; j < 4; ++j) acc[i][j] = f32x4{0.f, 0.f, 0.f, 0.f};

  float pf[16];

  // ---- helpers as lambdas (fully unrolled, static indexing) ----
  auto load_pf = [&](int t) {
#pragma unroll
    for (int i = 0; i < 16; ++i)
      pf[i] = imgb[(size_t)(t * kKT + c0 + i) * kP + px];
  };
  auto split_write = [&](int buf) {
    unsigned ph[8], pl[8];
#pragma unroll
    for (int i = 0; i < 8; ++i) {
      const unsigned a = __float_as_uint(pf[2 * i]);
      const unsigned c = __float_as_uint(pf[2 * i + 1]);
      const unsigned am = a & 0xFFFF0000u, cm = c & 0xFFFF0000u;
      ph[i] = (a >> 16) | cm;  // hi = trunc16 (Dekker: residual exact)
      const float la = __uint_as_float(a) - __uint_as_float(am);
      const float lc = __uint_as_float(c) - __uint_as_float(cm);
      pl[i] = (__float_as_uint(la) >> 16) | (__float_as_uint(lc) & 0xFFFF0000u);
    }
    *(u32x4*)(smem + afrag(buf, 0, skc, sg0, px)) = u32x4{ph[0], ph[1], ph[2], ph[3]};
    *(u32x4*)(smem + afrag(buf, 0, skc, sg0 + 1, px)) = u32x4{ph[4], ph[5], ph[6], ph[7]};
    *(u32x4*)(smem + afrag(buf, 1, skc, sg0, px)) = u32x4{pl[0], pl[1], pl[2], pl[3]};
    *(u32x4*)(smem + afrag(buf, 1, skc, sg0 + 1, px)) = u32x4{pl[4], pl[5], pl[6], pl[7]};
  };

  // ---- prologue: stage step 0 ----
  load_pf(0);
  split_write(0);
  __syncthreads();

  for (int t = 0; t < kSteps; ++t) {
    const int buf = t & 1;
    if (t + 1 < kSteps) load_pf(t + 1);  // issue early (T14): hides under MFMA

#pragma unroll
    for (int kc = 0; kc < 2; ++kc) {
      bf16x8 ah[4], al[4];
#pragma unroll
      for (int mt = 0; mt < 4; ++mt) {
        ah[mt] = *(const bf16x8*)(smem + afrag(buf, 0, kc, g, mt * 16 + m_l));
        al[mt] = *(const bf16x8*)(smem + afrag(buf, 1, kc, g, mt * 16 + m_l));
      }
#pragma unroll
      for (int ni = 0; ni < 4; ++ni) {
        const int nt = ni * 4 + wid;
        if (nt < kNT) {
          const unsigned short* bp =
              wsb + ((size_t)(t * 2 + kc) * 14 + nt) * 512 + lane * 8;
          const bf16x8 bh = *(const bf16x8*)bp;
          const bf16x8 bl = *(const bf16x8*)(bp + kWsHalf);
#pragma unroll
          for (int mt = 0; mt < 4; ++mt) {
            acc[ni][mt] = __builtin_amdgcn_mfma_f32_16x16x32_bf16(
                ah[mt], bh, acc[ni][mt], 0, 0, 0);
            acc[ni][mt] = __builtin_amdgcn_mfma_f32_16x16x32_bf16(
                ah[mt], bl, acc[ni][mt], 0, 0, 0);
            acc[ni][mt] = __builtin_amdgcn_mfma_f32_16x16x32_bf16(
                al[mt], bh, acc[ni][mt], 0, 0, 0);
          }
        }
      }
    }
    __syncthreads();  // everyone done reading buf (and prev writes of buf^1)
    if (t + 1 < kSteps) split_write(buf ^ 1);  // write late, after barrier
    __syncthreads();
  }

  // ---- epilogue: logits + bias -> d_out hm region [b][o][px] ----
#pragma unroll
  for (int ni = 0; ni < 4; ++ni) {
    const int nt = ni * 4 + wid;
    if (nt < kNT) {
      const int o = nt * 16 + m_l;
      if (o < kO) {
        const float bo = bias[o];
#pragma unroll
        for (int mt = 0; mt < 4; ++mt) {
          f32x4 v;
#pragma unroll
          for (int r = 0; r < 4; ++r) v[r] = acc[ni][mt][r] + bo;
          *(f32x4*)(out + ((size_t)b * kO + o) * 64 + mt * 16 + g * 4) = v;
        }
      }
    }
  }
}

// ---- K2: in-place softmax + soft-argmax; one wave per (b, joint) ----
__global__ __launch_bounds__(256) void softmax_kernel(float* __restrict__ out) {
  const int b = blockIdx.x;
  const int j = blockIdx.y * 4 + (threadIdx.x >> 6);
  const int lane = threadIdx.x & 63;
  if (j >= kJ) return;

  float* base = out + ((size_t)b * kJ + j) * 512;  // == [b][o=j*8+d][px]
  float v[8];
#pragma unroll
  for (int k = 0; k < 8; ++k) v[k] = base[k * 64 + lane];

  float m = v[0];
#pragma unroll
  for (int k = 1; k < 8; ++k) m = fmaxf(m, v[k]);
#pragma unroll
  for (int off = 32; off > 0; off >>= 1) m = fmaxf(m, __shfl_xor(m, off));

  float e[8];
  float s = 0.f;
#pragma unroll
  for (int k = 0; k < 8; ++k) {
    e[k] = __expf(v[k] - m);
    s += e[k];
  }
#pragma unroll
  for (int off = 32; off > 0; off >>= 1) s += __shfl_xor(s, off);
  const float inv = 1.0f / s;

  float psum = 0.f, zsum = 0.f;
#pragma unroll
  for (int k = 0; k < 8; ++k) {
    const float pv = e[k] * inv;
    base[k * 64 + lane] = pv;  // in-place, own-slice only
    psum += pv;
    zsum += (float)k * pv;
  }
  float xs = (float)(lane & 7) * psum;   // px = h*8+w -> w = lane&7
  float ys = (float)(lane >> 3) * psum;  // h = lane>>3
#pragma unroll
  for (int off = 32; off > 0; off >>= 1) {
    xs += __shfl_xor(xs, off);
    ys += __shfl_xor(ys, off);
    zsum += __shfl_xor(zsum, off);
  }
  if (lane == 0) {
    float* cd = out + kHmOut + ((size_t)b * kJ + j) * 3;
    cd[0] = xs;
    cd[1] = ys;
    cd[2] = zsum;
  }
}

extern "C" void kernel_launch(void* const* d_in, const int* in_sizes, int n_in,
                              void* d_out, int out_size, void* d_ws,
                              size_t ws_size, hipStream_t stream) {
  const float* img = (const float*)d_in[0];     // [512,768,8,8]
  const float* w = (const float*)d_in[1];       // [200,768]
  const float* bias = (const float*)d_in[2];    // [200]
  unsigned short* wsb = (unsigned short*)d_ws;  // 688,128 B
  float* out = (float*)d_out;

  weight_split_kernel<<<dim3(168), dim3(256), 0, stream>>>(w, wsb);
  gemm_kernel<<<dim3(kB), dim3(256), 0, stream>>>(img, wsb, bias, out);
  softmax_kernel<<<dim3(kB, 7), dim3(256), 0, stream>>>(out);
}

// Round 8
// 170.690 us; speedup vs baseline: 1.1680x; 1.1680x over previous
//
#include <hip/hip_runtime.h>

// PositionNet fused, fp16 single-term MFMA edition.
//   K0: w[200][768] fp32 -> ws fp16, fragment-major (344,064 B of d_ws)
//   K1: per-sample fused GEMM + softmax + soft-argmax.
//       512 blocks x 512 threads (8 waves = 2 M-halves x 4 N-groups).
//       A (img) -> fp16, double-buffered fragment-major LDS (16 KB),
//       ONE barrier per K-step; B direct global->VGPR (L2-hot, 1 KiB/frag).
//       Logits (+bias) -> 52 KB LDS hm (union over staging), then per-wave
//       softmax(512) + soft-argmax -> d_out.
//
// Numerics: fp16 inputs, fp32 MFMA accumulate. Derived logit RMS err ~2e-4
// (max ~1e-3) -> coord err ~3e-3 on top of the 0.0156 baseline absmax.
// Fallback if tolerance fails: re-add a w_lo fp16 term (2-term), same
// structure (~4 us extra matrix-pipe time, mostly hidden).
// Fragment k-addressing identical for A and B (k = kc*32 + (lane>>4)*8 + e),
// so any HW k-slot permutation cancels; relies only on lane&15 = free-dim and
// the validated C/D layout (col=lane&15, row=(lane>>4)*4+reg) from rounds 3-4.

typedef __attribute__((ext_vector_type(4))) float f32x4;
typedef _Float16 f16x8 __attribute__((ext_vector_type(8)));
typedef unsigned short us8 __attribute__((ext_vector_type(8)));

namespace {
constexpr int kB = 512, kC = 768, kP = 64, kO = 200, kJ = 25;
constexpr int kSteps = 12;  // K = 12 steps x 64 channels
constexpr int kNT = 13;     // live 16-wide N tiles (padded to 14 in ws)
constexpr int kHR = 65;     // hm row stride (floats): 65%32=1 -> <=4-way wr
constexpr int kWsFrag8 = 12 * 2 * 14 * 64;  // 21504 8-elem fragments in ws
constexpr size_t kHmOut = (size_t)kB * kJ * 512;
constexpr int kSmemBytes = kO * kHR * 4;  // 52000 B (hm view > 16 KB staging)
}  // namespace

// ---- K0: w -> fp16 fragment-major [t*2+kc][nt(14)][lane][e8] ----
__global__ __launch_bounds__(256) void weight_half_kernel(
    const float* __restrict__ w, unsigned short* __restrict__ ws) {
  const int id = blockIdx.x * 256 + threadIdx.x;
  if (id >= kWsFrag8) return;
  const int ml = id & 15, g = (id >> 4) & 3;
  const int id2 = id >> 6;
  const int nt = id2 % 14;
  const int q = id2 / 14;  // q = t*2 + kc
  const int n = nt * 16 + ml;
  const int kb = q * 32 + g * 8;  // t*64 + kc*32 + g*8
  union { _Float16 h[8]; us8 u; } pk;
#pragma unroll
  for (int i = 0; i < 8; ++i) {
    const float v = (n < kO) ? w[(size_t)n * kC + kb + i] : 0.f;
    pk.h[i] = (_Float16)v;  // RNE
  }
  *(us8*)(ws + (size_t)id * 8) = pk.u;  // dst layout == id order
}

// A LDS cell (shorts index): [buf][kc][g][px] x 8 fp16 (16 B)
__device__ inline int acell(int buf, int kc, int g, int px) {
  return (((buf * 2 + kc) * 4 + g) * 64 + px) * 8;
}

__global__ __launch_bounds__(512, 4) void posnet_fused_kernel(
    const float* __restrict__ img, const unsigned short* __restrict__ wsb,
    const float* __restrict__ bias, float* __restrict__ out) {
  __shared__ __align__(16) char smem[kSmemBytes];  // union: A staging | hm
  unsigned short* aLds = (unsigned short*)smem;
  float* hm = (float*)smem;

  const int b = blockIdx.x;
  const int tid = threadIdx.x;
  const int lane = tid & 63;
  const int wid = tid >> 6;  // 0..7
  const int ng = __builtin_amdgcn_readfirstlane(wid & 3);   // N-group
  const int mh = __builtin_amdgcn_readfirstlane(wid >> 2);  // M-half
  const int m_l = lane & 15;
  const int g = lane >> 4;
  const float* __restrict__ imgb = img + (size_t)b * kC * kP;

  // staging coords: px = lane; 8-channel slice c0 = wid*8 within the K-tile
  const int sc0 = wid * 8;
  const int skc = sc0 >> 5;         // 0..1
  const int sg = (sc0 & 31) >> 3;   // 0..3

  f32x4 acc[4][2];  // [ni][mt-within-half]
#pragma unroll
  for (int i = 0; i < 4; ++i)
#pragma unroll
    for (int j = 0; j < 2; ++j) acc[i][j] = f32x4{0.f, 0.f, 0.f, 0.f};

  float pf[8];
  auto load_pf = [&](int t) {  // 8 coalesced fp32 loads, issued early (T14)
#pragma unroll
    for (int i = 0; i < 8; ++i)
      pf[i] = imgb[(size_t)(t * 64 + sc0 + i) * kP + lane];
  };
  auto cvt_write = [&](int buf) {  // fp32 -> fp16, one 16 B conflict-free write
    union { _Float16 h[8]; us8 u; } pk;
#pragma unroll
    for (int i = 0; i < 8; ++i) pk.h[i] = (_Float16)pf[i];
    *(us8*)(aLds + acell(buf, skc, sg, lane)) = pk.u;
  };

  load_pf(0);
  cvt_write(0);
  __syncthreads();

  for (int t = 0; t < kSteps; ++t) {
    const int buf = t & 1;
    if (t + 1 < kSteps) load_pf(t + 1);  // hide HBM latency under MFMAs
#pragma unroll
    for (int kc = 0; kc < 2; ++kc) {
      // A fragments: rows mh*32+m_l and mh*32+16+m_l (single b128 each)
      const f16x8 a0 = *(const f16x8*)(aLds + acell(buf, kc, g, mh * 32 + m_l));
      const f16x8 a1 =
          *(const f16x8*)(aLds + acell(buf, kc, g, mh * 32 + 16 + m_l));
#pragma unroll
      for (int ii = 0; ii < 4; ++ii) {
        const int nt = ii * 4 + ng;
        if (nt < kNT) {
          const f16x8 bb = *(const f16x8*)(
              wsb + ((size_t)(t * 2 + kc) * 14 + nt) * 512 + lane * 8);
          acc[ii][0] =
              __builtin_amdgcn_mfma_f32_16x16x32_f16(a0, bb, acc[ii][0], 0, 0, 0);
          acc[ii][1] =
              __builtin_amdgcn_mfma_f32_16x16x32_f16(a1, bb, acc[ii][1], 0, 0, 0);
        }
      }
    }
    // write NEXT tile into the other buffer (prev readers already done at the
    // barrier of t-1; current readers use `buf` only) -> one barrier/step
    if (t + 1 < kSteps) cvt_write((t + 1) & 1);
    __syncthreads();
  }

  // ---- epilogue: logits + bias -> hm LDS (smem reused; reads drained) ----
#pragma unroll
  for (int ii = 0; ii < 4; ++ii) {
    const int nt = ii * 4 + ng;
    if (nt < kNT) {
      const int o = nt * 16 + m_l;
      if (o < kO) {
        const float bo = bias[o];
#pragma unroll
        for (int mt = 0; mt < 2; ++mt) {
          const int m = (mh * 2 + mt) * 16 + g * 4;
#pragma unroll
          for (int r = 0; r < 4; ++r) hm[o * kHR + m + r] = acc[ii][mt][r] + bo;
        }
      }
    }
  }
  __syncthreads();

  // ---- softmax over 512 + soft-argmax; 25 joints over 8 waves ----
  for (int j = wid; j < kJ; j += 8) {
    float v[8];
#pragma unroll
    for (int k = 0; k < 8; ++k) v[k] = hm[(j * 8 + k) * kHR + lane];

    float m = v[0];
#pragma unroll
    for (int k = 1; k < 8; ++k) m = fmaxf(m, v[k]);
#pragma unroll
    for (int off = 32; off > 0; off >>= 1) m = fmaxf(m, __shfl_xor(m, off));

    float e[8];
    float s = 0.f;
#pragma unroll
    for (int k = 0; k < 8; ++k) {
      e[k] = __expf(v[k] - m);
      s += e[k];
    }
#pragma unroll
    for (int off = 32; off > 0; off >>= 1) s += __shfl_xor(s, off);
    const float inv = 1.0f / s;

    float psum = 0.f, zsum = 0.f;
    float* dst = out + ((size_t)b * kJ + j) * 512;
#pragma unroll
    for (int k = 0; k < 8; ++k) {
      const float pv = e[k] * inv;
      dst[k * 64 + lane] = pv;  // coalesced 256 B stores
      psum += pv;
      zsum += (float)k * pv;    // depth index = k
    }
    float xs = (float)(lane & 7) * psum;   // px = h*8+w -> w = lane&7
    float ys = (float)(lane >> 3) * psum;  // h = lane>>3
#pragma unroll
    for (int off = 32; off > 0; off >>= 1) {
      xs += __shfl_xor(xs, off);
      ys += __shfl_xor(ys, off);
      zsum += __shfl_xor(zsum, off);
    }
    if (lane == 0) {
      float* cd = out + kHmOut + ((size_t)b * kJ + j) * 3;
      cd[0] = xs;
      cd[1] = ys;
      cd[2] = zsum;
    }
  }
}

extern "C" void kernel_launch(void* const* d_in, const int* in_sizes, int n_in,
                              void* d_out, int out_size, void* d_ws,
                              size_t ws_size, hipStream_t stream) {
  const float* img = (const float*)d_in[0];     // [512,768,8,8]
  const float* w = (const float*)d_in[1];       // [200,768]
  const float* bias = (const float*)d_in[2];    // [200]
  unsigned short* wsb = (unsigned short*)d_ws;  // 344,064 B used
  float* out = (float*)d_out;

  weight_half_kernel<<<dim3((kWsFrag8 + 255) / 256), dim3(256), 0, stream>>>(w, wsb);
  posnet_fused_kernel<<<dim3(kB), dim3(512), 0, stream>>>(img, wsb, bias, out);
}